// Round 5
// baseline (617.203 us; speedup 1.0000x reference)
//
#include <hip/hip_runtime.h>
#include <hip/hip_bf16.h>
#include <math.h>

#define NROWS 8192
#define DIM   1024
#define CAP   256
#define MARGIN 120.0f

using f16x8 = __attribute__((ext_vector_type(8))) _Float16;
using f32x4 = __attribute__((ext_vector_type(4))) float;
typedef unsigned short u16;
typedef unsigned int   u32;

#define AS1 __attribute__((address_space(1)))
#define AS3 __attribute__((address_space(3)))

// ---------------- split fp32 array (len % 1024 == 0) into hi/lo fp16 planes ----
// fp16 2-split carries ~22 mantissa bits: hi + lo with lo = fp16(x - (float)hi).
__global__ __launch_bounds__(256) void split2h(const float* __restrict__ X,
                                               u16* __restrict__ H,
                                               u16* __restrict__ L) {
    const int idx = (blockIdx.x * 256 + threadIdx.x) * 4;
    float4 x = *(const float4*)&X[idx];
    float c[4] = {x.x, x.y, x.z, x.w};
    u16 h[4], l[4];
#pragma unroll
    for (int i = 0; i < 4; ++i) {
        _Float16 hh = (_Float16)c[i];
        float r = c[i] - (float)hh;
        _Float16 ll = (_Float16)r;
        h[i] = *(u16*)&hh; l[i] = *(u16*)&ll;
    }
    *(ushort4*)&H[idx] = make_ushort4(h[0], h[1], h[2], h[3]);
    *(ushort4*)&L[idx] = make_ushort4(l[0], l[1], l[2], l[3]);
}

// ---------------- transpose Wv, keep hi fp16 plane: Wvth[c][d] = f16(Wv[d][c]) -
__global__ __launch_bounds__(256) void split_wvt(const float* __restrict__ W,
                                                 u16* __restrict__ H) {
    __shared__ float t[64][65];
    const int k0 = blockIdx.x * 64, n0 = blockIdx.y * 64;
    const int c = threadIdx.x & 63, r4 = threadIdx.x >> 6;
#pragma unroll
    for (int i = 0; i < 16; ++i) {
        int k = r4 + i * 4;
        t[k][c] = W[(size_t)(k0 + k) * DIM + n0 + c];
    }
    __syncthreads();
#pragma unroll
    for (int i = 0; i < 16; ++i) {
        int n = r4 + i * 4;
        _Float16 hb = (_Float16)t[c][n];
        H[(n0 + n) * DIM + k0 + c] = *(u16*)&hb;
    }
}

// ---------------- shared LDS-dbuf 128x128 NT fp16 GEMM engine, BK=32 -----------
// R4-proven m97 regime (32 KiB LDS -> 4 blocks/CU; cross-block TLP hides the
// barrier drain) + R5 strength reduction: the R4 profile showed VALUBusy 40%
// vs MfmaUtil 24% -- ~40 VALU/iter of address math sharing issue slots with
// MFMA. v2: chunk loop unrolled by 2 so the dbuf index is a compile-time
// literal (ds_read fragment addresses become loop-invariant, hoisted) and the
// 4 global_load_lds sources are walking pointers (+32 elts per chunk) instead
// of per-iter 64-bit recomputation. Product-transition iteration peeled so the
// hot body is branch-free. Bank-conflict swizzle (proven: 1.68e7 -> 0):
// source chunk pre-swizzled (lane&3)^((lane>>3)&3), read col (quad^((r16>>1)&3)).
template<int NP>
__device__ __forceinline__ void gemm_lds(const u16* const (&Ap)[NP],
                                         const u16* const (&Bp)[NP],
                                         int row0, int col0, f32x4 (&acc)[4][4],
                                         short (&As)[2][4096], short (&Bs)[2][4096]) {
    const int tid = threadIdx.x;
    const int w = tid >> 6, lane = tid & 63;
    const int wy = w >> 1, wx = w & 1;
    const int quad = lane >> 4, r16 = lane & 15;

    // staging map: lane l covers tile row w*32 + (l>>2) (+16 for the second
    // instruction), source 16B chunk pre-swizzled; HW appends lane*16B to the
    // wave-uniform LDS base -> row-major [row][32 shorts].
    const int    srow   = w * 32 + (lane >> 2);
    const int    schunk = ((lane & 3) ^ ((lane >> 3) & 3)) * 8;
    const size_t gA0 = (size_t)(row0 + srow) * DIM + schunk;
    const size_t gB0 = (size_t)(col0 + srow) * DIM + schunk;
    const int lds0 = (w * 32) * 32;
    const int lds1 = (w * 32 + 16) * 32;

    // walking source pointers: always point at the NEXT chunk to stage
    const u16 *sA0, *sA1, *sB0, *sB1;
    auto setp = [&](const u16* A, const u16* B) {
        sA0 = A + gA0; sA1 = sA0 + (size_t)16 * DIM;
        sB0 = B + gB0; sB1 = sB0 + (size_t)16 * DIM;
    };
    auto issue2 = [&](int buf) {   // stage one 32-k chunk, advance pointers
        __builtin_amdgcn_global_load_lds((const AS1 u32*)sA0, (AS3 u32*)&As[buf][lds0], 16, 0, 0);
        __builtin_amdgcn_global_load_lds((const AS1 u32*)sA1, (AS3 u32*)&As[buf][lds1], 16, 0, 0);
        __builtin_amdgcn_global_load_lds((const AS1 u32*)sB0, (AS3 u32*)&Bs[buf][lds0], 16, 0, 0);
        __builtin_amdgcn_global_load_lds((const AS1 u32*)sB1, (AS3 u32*)&Bs[buf][lds1], 16, 0, 0);
        sA0 += 32; sA1 += 32; sB0 += 32; sB1 += 32;
    };

    const int ccol = (quad ^ ((r16 >> 1) & 3)) * 8;   // swizzled read column

    auto compute = [&](const short* __restrict__ AsC, const short* __restrict__ BsC) {
        f16x8 af[4], bfr[4];
#pragma unroll
        for (int m = 0; m < 4; ++m)
            af[m] = *(const f16x8*)&AsC[(wy * 64 + m * 16 + r16) * 32 + ccol];
#pragma unroll
        for (int n = 0; n < 4; ++n)
            bfr[n] = *(const f16x8*)&BsC[(wx * 64 + n * 16 + r16) * 32 + ccol];
#pragma unroll
        for (int m = 0; m < 4; ++m)
#pragma unroll
            for (int n = 0; n < 4; ++n)
                acc[m][n] = __builtin_amdgcn_mfma_f32_16x16x32_f16(af[m], bfr[n], acc[m][n], 0, 0, 0);
    };

    setp(Ap[0], Bp[0]);
    issue2(0);                         // chunk 0 -> buf0; pointers at chunk 1

#pragma unroll
    for (int p = 0; p < NP; ++p) {
        const bool more = (p + 1 < NP);
        // 15 branch-free double-chunks: chunks {2ii,2ii+1} in bufs {0,1}
#pragma unroll 1
        for (int ii = 0; ii < 15; ++ii) {
            __syncthreads();
            issue2(1);                 // stage odd chunk
            compute(As[0], Bs[0]);
            __syncthreads();
            issue2(0);                 // stage next even chunk
            compute(As[1], Bs[1]);
        }
        // peeled tail: chunks 30,31 (+ next product's chunk 0)
        __syncthreads();
        issue2(1);                     // chunk 31 -> buf1
        compute(As[0], Bs[0]);
        __syncthreads();
        if (more) { setp(Ap[p + 1], Bp[p + 1]); issue2(0); }
        compute(As[1], Bs[1]);
    }
}

// ---------------- Gt = Wk @ Wq^T (fp32 out, Gt[c][d] = (Wq Wk^T)[d][c]) --------
// fp16 2-split: 3 products {lh, hl, hh} carry ~22 bits (ll dropped, rel 2^-22).
__global__ __launch_bounds__(256) void g_gemm(const u16* __restrict__ Wkh, const u16* __restrict__ Wkl,
                                              const u16* __restrict__ Wqh, const u16* __restrict__ Wql,
                                              float* __restrict__ Gt) {
    __shared__ short As[2][4096], Bs[2][4096];
    const int tid = threadIdx.x, w = tid >> 6, lane = tid & 63;
    const int wy = w >> 1, wx = w & 1, quad = lane >> 4, r16 = lane & 15;
    const int row0 = blockIdx.y * 128, col0 = blockIdx.x * 128;
    const u16* const Ap[3] = { Wkl, Wkh, Wkh };   // lh, hl, hh (small -> large)
    const u16* const Bp[3] = { Wqh, Wql, Wqh };
    f32x4 acc[4][4] = {};
    gemm_lds<3>(Ap, Bp, row0, col0, acc, As, Bs);
#pragma unroll
    for (int m = 0; m < 4; ++m)
#pragma unroll
        for (int n = 0; n < 4; ++n)
#pragma unroll
            for (int reg = 0; reg < 4; ++reg) {
                const int row = row0 + wy * 64 + m * 16 + quad * 4 + reg;
                const int col = col0 + wx * 64 + n * 16 + r16;
                Gt[row * DIM + col] = acc[m][n][reg];
            }
}

// ---------------- id<512: Y = X@G (fp32+fp16) ; id>=512: Vh = Xh@Wvt_h ---------
// id = z*512 + colt*64 + rowt -> id%8 == rowt%8: XCD round-robin pins each
// XCD's 8 A-row-tiles in its L2 (proven: FETCH 918 -> 87 MB class of fix).
__global__ __launch_bounds__(256) void yv_gemm(const u16* __restrict__ Xh, const u16* __restrict__ Xl,
                                               const u16* __restrict__ Gth, const u16* __restrict__ Gtl,
                                               const u16* __restrict__ Wvth,
                                               float* __restrict__ Y, u16* __restrict__ Yh, u16* __restrict__ Vh) {
    __shared__ short As[2][4096], Bs[2][4096];
    const int tid = threadIdx.x, w = tid >> 6, lane = tid & 63;
    const int wy = w >> 1, wx = w & 1, quad = lane >> 4, r16 = lane & 15;
    const int id = blockIdx.x;
    const int z = id >> 9;
    const int within = id & 511;
    const int colt = within >> 6;          // 0..7
    const int rowt = within & 63;          // 0..63
    const int row0 = rowt * 128, col0 = colt * 128;
    f32x4 acc[4][4] = {};
    if (z == 0) {
        const u16* const Ap[3] = { Xl,  Xh,  Xh  };   // lh, hl, hh
        const u16* const Bp[3] = { Gth, Gtl, Gth };
        gemm_lds<3>(Ap, Bp, row0, col0, acc, As, Bs);
#pragma unroll
        for (int m = 0; m < 4; ++m)
#pragma unroll
            for (int n = 0; n < 4; ++n)
#pragma unroll
                for (int reg = 0; reg < 4; ++reg) {
                    const int row = row0 + wy * 64 + m * 16 + quad * 4 + reg;
                    const int col = col0 + wx * 64 + n * 16 + r16;
                    float v = acc[m][n][reg];
                    Y[row * DIM + col] = v;
                    _Float16 hb = (_Float16)v;
                    Yh[row * DIM + col] = *(u16*)&hb;
                }
    } else {
        const u16* const Ap[1] = { Xh };
        const u16* const Bp[1] = { Wvth };
        gemm_lds<1>(Ap, Bp, row0, col0, acc, As, Bs);
#pragma unroll
        for (int m = 0; m < 4; ++m)
#pragma unroll
            for (int n = 0; n < 4; ++n)
#pragma unroll
                for (int reg = 0; reg < 4; ++reg) {
                    const int row = row0 + wy * 64 + m * 16 + quad * 4 + reg;
                    const int col = col0 + wx * 64 + n * 16 + r16;
                    _Float16 hb = (_Float16)acc[m][n][reg];
                    Vh[row * DIM + col] = *(u16*)&hb;
                }
    }
}

// ---------------- filter: S = Yh @ Xh^T (fp16), per-64col-group margin emit ----
// fp16 score error sigma ~ 10 -> MARGIN 120 (>9 sigma slack over the e^-30
// relevance window). Group max is always emitted, so the global argmax and any
// same/other-group runner-up always survive.
__global__ __launch_bounds__(256) void filter_kernel(const u16* __restrict__ Yhp,
                                                     const u16* __restrict__ Xhp,
                                                     int* __restrict__ cnt,
                                                     int2* __restrict__ cand) {
    __shared__ short As[2][4096], Bs[2][4096];
    const int tid = threadIdx.x, w = tid >> 6, lane = tid & 63;
    const int wy = w >> 1, wx = w & 1, quad = lane >> 4, r16 = lane & 15;
    const int id = blockIdx.x;
    const int colt = id >> 6;              // 0..63 ; id%8 == rowt%8 (XCD pin)
    const int rowt = id & 63;              // 0..63
    const int row0 = rowt * 128, col0 = colt * 128;

    const u16* const Ap[1] = { Yhp };
    const u16* const Bp[1] = { Xhp };
    f32x4 acc[4][4] = {};
    gemm_lds<1>(Ap, Bp, row0, col0, acc, As, Bs);

    // per row: 64-col group max -> margin filter -> emit (mechanics proven)
#pragma unroll
    for (int m = 0; m < 4; ++m) {
#pragma unroll
        for (int reg = 0; reg < 4; ++reg) {
            float mx = fmaxf(fmaxf(acc[m][0][reg], acc[m][1][reg]),
                             fmaxf(acc[m][2][reg], acc[m][3][reg]));
            mx = fmaxf(mx, __shfl_xor(mx, 1, 64));
            mx = fmaxf(mx, __shfl_xor(mx, 2, 64));
            mx = fmaxf(mx, __shfl_xor(mx, 4, 64));
            mx = fmaxf(mx, __shfl_xor(mx, 8, 64));
            const float th = mx - MARGIN;
            const int row = row0 + wy * 64 + m * 16 + quad * 4 + reg;
#pragma unroll
            for (int n = 0; n < 4; ++n) {
                float s = acc[m][n][reg];
                if (s >= th) {
                    int pos = atomicAdd(&cnt[row], 1);
                    if (pos < CAP)
                        cand[(size_t)row * CAP + pos] =
                            make_int2(col0 + wx * 64 + n * 16 + r16, __float_as_int(s));
                }
            }
        }
    }
}

// ---------------- finalize: refilter, fp64 rescore via Y·X, softmax, gather Vh -
__global__ __launch_bounds__(256) void finalize_kernel(const float* __restrict__ Y,
                                                       const float* __restrict__ X,
                                                       const u16* __restrict__ Vh,
                                                       const int* __restrict__ cnt,
                                                       const int2* __restrict__ cand,
                                                       float* __restrict__ out) {
    const int i = blockIdx.x;
    const int tid = threadIdx.x;
    const int w = tid >> 6, lane = tid & 63;
    __shared__ float  red[256];
    __shared__ int    surv[64];
    __shared__ double sprec[64];
    __shared__ float  wgt[64];
    __shared__ int    nsurv;

    const int c = min(cnt[i], CAP);
    float m = -3.0e38f;
    for (int t = tid; t < c; t += 256)
        m = fmaxf(m, __int_as_float(cand[(size_t)i * CAP + t].y));
    red[tid] = m;
    __syncthreads();
    for (int s = 128; s > 0; s >>= 1) {
        if (tid < s) red[tid] = fmaxf(red[tid], red[tid + s]);
        __syncthreads();
    }
    const float th = red[0] - MARGIN;
    if (tid == 0) nsurv = 0;
    __syncthreads();
    for (int t = tid; t < c; t += 256) {
        int2 e = cand[(size_t)i * CAP + t];
        if (__int_as_float(e.y) >= th) {
            int p = atomicAdd(&nsurv, 1);
            if (p < 64) surv[p] = e.x;
        }
    }
    __syncthreads();
    const int ns = min(nsurv, 64);
    // fp64 rescore: s_ij = y_i . x_j (exact given fp32 Y), one survivor per wave
    for (int u = w; u < ns; u += 4) {
        const int j = surv[u];
        double a = 0.0;
#pragma unroll 1
        for (int d4 = lane; d4 < DIM / 4; d4 += 64) {
            float4 yv = *(const float4*)&Y[(size_t)i * DIM + d4 * 4];
            float4 xv = *(const float4*)&X[(size_t)j * DIM + d4 * 4];
            a += (double)yv.x * (double)xv.x + (double)yv.y * (double)xv.y
               + (double)yv.z * (double)xv.z + (double)yv.w * (double)xv.w;
        }
#pragma unroll
        for (int o = 32; o > 0; o >>= 1)
            a += __shfl_down(a, o, 64);
        if (lane == 0) sprec[u] = a;
    }
    __syncthreads();
    if (tid == 0) {
        double mm = -1.0e300;
        for (int u = 0; u < ns; ++u) mm = fmax(mm, sprec[u]);
        double l = 0.0;
        for (int u = 0; u < ns; ++u) l += exp(sprec[u] - mm);
        for (int u = 0; u < ns; ++u) wgt[u] = (float)(exp(sprec[u] - mm) / l);
    }
    __syncthreads();
    // gather: 2 bf16 per thread per pass (coalesced 4B/lane)
    for (int d2 = tid; d2 < DIM / 2; d2 += 256) {
        float o0 = 0.f, o1 = 0.f;
        for (int u = 0; u < ns; ++u) {
            const u16* vp = &Vh[(size_t)surv[u] * DIM + d2 * 2];
            u32 pair = *(const u32*)vp;
            _Float16 h0 = *(_Float16*)&pair;
            u16 hi = (u16)(pair >> 16);
            _Float16 h1 = *(_Float16*)&hi;
            o0 += wgt[u] * (float)h0;
            o1 += wgt[u] * (float)h1;
        }
        out[(size_t)i * DIM + d2 * 2]     = o0;
        out[(size_t)i * DIM + d2 * 2 + 1] = o1;
    }
}

extern "C" void kernel_launch(void* const* d_in, const int* in_sizes, int n_in,
                              void* d_out, int out_size, void* d_ws, size_t ws_size,
                              hipStream_t stream) {
    const float* X  = (const float*)d_in[0];
    const float* wq = (const float*)d_in[1];
    const float* wk = (const float*)d_in[2];
    const float* wv = (const float*)d_in[3];
    float* out = (float*)d_out;

    char* ws = (char*)d_ws;
    const size_t MB = 1024 * 1024;
    u16*   Xh   = (u16*)(ws +   0 * MB);   // 16 MB
    u16*   Xl   = (u16*)(ws +  16 * MB);   // 16 MB
    u16*   Wqh  = (u16*)(ws +  32 * MB);   // 2 MB each
    u16*   Wql  = (u16*)(ws +  34 * MB);
    u16*   Wkh  = (u16*)(ws +  36 * MB);
    u16*   Wkl  = (u16*)(ws +  38 * MB);
    u16*   Wvth = (u16*)(ws +  40 * MB);
    float* Gt   = (float*)(ws + 42 * MB);  // 4 MB fp32 [c][d]
    u16*   Gth  = (u16*)(ws +  46 * MB);
    u16*   Gtl  = (u16*)(ws +  48 * MB);
    float* Y    = (float*)(ws + 64 * MB);  // 32 MB
    u16*   Yh   = (u16*)(ws +  96 * MB);   // 16 MB
    u16*   Vh   = (u16*)(ws + 112 * MB);   // 16 MB
    int*   cnt  = (int*)(ws + 128 * MB);   // 32 KB
    int2*  cand = (int2*)(ws + 129 * MB);  // 8192*256*8 = 16.8 MB

    hipMemsetAsync(cnt, 0, (size_t)NROWS * 4, stream);

    split2h<<<NROWS * DIM / 1024, 256, 0, stream>>>(X, Xh, Xl);
    split2h<<<DIM * DIM / 1024, 256, 0, stream>>>(wq, Wqh, Wql);
    split2h<<<DIM * DIM / 1024, 256, 0, stream>>>(wk, Wkh, Wkl);
    split_wvt<<<dim3(16, 16), 256, 0, stream>>>(wv, Wvth);

    g_gemm<<<dim3(8, 8), 256, 0, stream>>>(Wkh, Wkl, Wqh, Wql, Gt);
    split2h<<<DIM * DIM / 1024, 256, 0, stream>>>(Gt, Gth, Gtl);

    yv_gemm<<<1024, 256, 0, stream>>>(Xh, Xl, Gth, Gtl, Wvth, Y, Yh, Vh);

    filter_kernel<<<4096, 256, 0, stream>>>(Yh, Xh, cnt, cand);

    finalize_kernel<<<NROWS, 256, 0, stream>>>(Y, X, Vh, cnt, cand, out);
}

// Round 6
// 527.462 us; speedup vs baseline: 1.1701x; 1.1701x over previous
//
#include <hip/hip_runtime.h>
#include <hip/hip_bf16.h>
#include <math.h>

#define NROWS 8192
#define DIM   1024
#define CAP   256
#define MARGIN 120.0f

using f16x8 = __attribute__((ext_vector_type(8))) _Float16;
using f32x4 = __attribute__((ext_vector_type(4))) float;
typedef unsigned short u16;
typedef unsigned int   u32;

#define AS1 __attribute__((address_space(1)))
#define AS3 __attribute__((address_space(3)))

// inline-asm LDS read: invisible to the compiler's LDS-alias waitcnt tracking,
// so the raw-s_barrier loop keeps its COUNTED vmcnt (no auto vmcnt(0) drain).
// Ordering vs MFMA enforced by lgkmcnt(0) + sched_barrier(0) (rule #18).
#define DS_READ_B128(dst, off) \
    asm volatile("ds_read_b128 %0, %1" : "=v"(dst) : "v"(off))

// ---------------- split fp32 array (len % 1024 == 0) into hi/lo fp16 planes ----
// fp16 2-split carries ~22 mantissa bits: hi + lo with lo = fp16(x - (float)hi).
__global__ __launch_bounds__(256) void split2h(const float* __restrict__ X,
                                               u16* __restrict__ H,
                                               u16* __restrict__ L) {
    const int idx = (blockIdx.x * 256 + threadIdx.x) * 4;
    float4 x = *(const float4*)&X[idx];
    float c[4] = {x.x, x.y, x.z, x.w};
    u16 h[4], l[4];
#pragma unroll
    for (int i = 0; i < 4; ++i) {
        _Float16 hh = (_Float16)c[i];
        float r = c[i] - (float)hh;
        _Float16 ll = (_Float16)r;
        h[i] = *(u16*)&hh; l[i] = *(u16*)&ll;
    }
    *(ushort4*)&H[idx] = make_ushort4(h[0], h[1], h[2], h[3]);
    *(ushort4*)&L[idx] = make_ushort4(l[0], l[1], l[2], l[3]);
}

// ---------------- transpose Wv, keep hi fp16 plane: Wvth[c][d] = f16(Wv[d][c]) -
__global__ __launch_bounds__(256) void split_wvt(const float* __restrict__ W,
                                                 u16* __restrict__ H) {
    __shared__ float t[64][65];
    const int k0 = blockIdx.x * 64, n0 = blockIdx.y * 64;
    const int c = threadIdx.x & 63, r4 = threadIdx.x >> 6;
#pragma unroll
    for (int i = 0; i < 16; ++i) {
        int k = r4 + i * 4;
        t[k][c] = W[(size_t)(k0 + k) * DIM + n0 + c];
    }
    __syncthreads();
#pragma unroll
    for (int i = 0; i < 16; ++i) {
        int n = r4 + i * 4;
        _Float16 hb = (_Float16)t[c][n];
        H[(n0 + n) * DIM + k0 + c] = *(u16*)&hb;
    }
}

// ---------------- R4-proven 2-buf engine (g_gemm only; small, off hot path) ---
template<int NP>
__device__ __forceinline__ void gemm_lds(const u16* const (&Ap)[NP],
                                         const u16* const (&Bp)[NP],
                                         int row0, int col0, f32x4 (&acc)[4][4],
                                         short (&As)[2][4096], short (&Bs)[2][4096]) {
    const int tid = threadIdx.x;
    const int w = tid >> 6, lane = tid & 63;
    const int wy = w >> 1, wx = w & 1;
    const int quad = lane >> 4, r16 = lane & 15;

    const int    srow   = w * 32 + (lane >> 2);
    const int    schunk = ((lane & 3) ^ ((lane >> 3) & 3)) * 8;
    const size_t gA0 = (size_t)(row0 + srow) * DIM + schunk;
    const size_t gA1 = gA0 + (size_t)16 * DIM;
    const size_t gB0 = (size_t)(col0 + srow) * DIM + schunk;
    const size_t gB1 = gB0 + (size_t)16 * DIM;
    const int lds0 = (w * 32) * 32;
    const int lds1 = (w * 32 + 16) * 32;

    auto issue = [&](const u16* A, const u16* B, size_t ko, int buf) {
        __builtin_amdgcn_global_load_lds((const AS1 u32*)(A + gA0 + ko), (AS3 u32*)&As[buf][lds0], 16, 0, 0);
        __builtin_amdgcn_global_load_lds((const AS1 u32*)(A + gA1 + ko), (AS3 u32*)&As[buf][lds1], 16, 0, 0);
        __builtin_amdgcn_global_load_lds((const AS1 u32*)(B + gB0 + ko), (AS3 u32*)&Bs[buf][lds0], 16, 0, 0);
        __builtin_amdgcn_global_load_lds((const AS1 u32*)(B + gB1 + ko), (AS3 u32*)&Bs[buf][lds1], 16, 0, 0);
    };

    issue(Ap[0], Bp[0], 0, 0);

    const int ccol = (quad ^ ((r16 >> 1) & 3)) * 8;

    int pp = 0;
#pragma unroll
    for (int p = 0; p < NP; ++p) {
        const u16* A = Ap[p];
        const u16* B = Bp[p];
        const u16* An = (p + 1 < NP) ? Ap[p + 1] : A;
        const u16* Bn = (p + 1 < NP) ? Bp[p + 1] : B;
        const bool more = (p + 1 < NP);
        for (int i = 0; i < 32; ++i) {
            __syncthreads();
            const int cur = pp, nxt = pp ^ 1;
            if (i < 31)      issue(A, B, (size_t)(i + 1) * 32, nxt);
            else if (more)   issue(An, Bn, 0, nxt);
            const short* AsC = As[cur];
            const short* BsC = Bs[cur];
            f16x8 af[4], bfr[4];
#pragma unroll
            for (int m = 0; m < 4; ++m)
                af[m] = *(const f16x8*)&AsC[(wy * 64 + m * 16 + r16) * 32 + ccol];
#pragma unroll
            for (int n = 0; n < 4; ++n)
                bfr[n] = *(const f16x8*)&BsC[(wx * 64 + n * 16 + r16) * 32 + ccol];
#pragma unroll
            for (int m = 0; m < 4; ++m)
#pragma unroll
                for (int n = 0; n < 4; ++n)
                    acc[m][n] = __builtin_amdgcn_mfma_f32_16x16x32_f16(af[m], bfr[n], acc[m][n], 0, 0, 0);
            pp ^= 1;
        }
    }
}

// ---------------- 128x128 NT fp16 engine, 3-buf counted-vmcnt pipeline --------
// R6: same tile/fragment/swizzle map as the R4 checkpoint (258 us filter), but
// the barrier no longer drains the prefetch. R4's __syncthreads lowers to
// s_waitcnt vmcnt(0): the tile staged one iter earlier is drained every iter,
// so slack = one compute phase (~150-300 cy) < L2/L3 latency -> ~70% stall
// (measured: 1209 cy/iter wall vs ~150 pipe demand). With 2 buffers a counted
// wait is impossible (the wait must cover the newest stage); 3 buffers (48 KiB,
// still 3 blocks/CU) give prefetch distance 2:
//   per iter g: vmcnt(4) [stage g done, stage g+1 stays in flight] -> raw
//   s_barrier -> stage(g+2) -> 8 asm ds_read -> lgkmcnt(0)+sched_barrier ->
//   16 MFMA. Loads now have ~2 iterations (~600+ cy) to land (T3/T4, m218).
// WAR safety: stage(g+2) overwrites buf (g+2)%3 = (g-1)%3, whose ds_reads
// completed before each wave's iter-(g-1) lgkmcnt(0); this iter's barrier
// orders that against the stage. Swizzle unchanged (conflicts 0 since R1).
// VGPR discipline (R5 lesson: arch 64->88 halved occupancy): no unroll, no
// walking pointers; __launch_bounds__(256,3) caps allocation.
template<int NP>
__device__ __forceinline__ void gemm_pipe(const u16* const (&Ap)[NP],
                                          const u16* const (&Bp)[NP],
                                          int row0, int col0, f32x4 (&acc)[4][4],
                                          short (&As)[3][4096], short (&Bs)[3][4096]) {
    const int tid = threadIdx.x;
    const int w = tid >> 6, lane = tid & 63;
    const int wy = w >> 1, wx = w & 1;
    const int quad = lane >> 4, r16 = lane & 15;

    const int    srow   = w * 32 + (lane >> 2);
    const int    schunk = ((lane & 3) ^ ((lane >> 3) & 3)) * 8;
    const size_t gA0 = (size_t)(row0 + srow) * DIM + schunk;
    const size_t gA1 = gA0 + (size_t)16 * DIM;
    const size_t gB0 = (size_t)(col0 + srow) * DIM + schunk;
    const size_t gB1 = gB0 + (size_t)16 * DIM;
    const int lds0 = (w * 32) * 32;
    const int lds1 = (w * 32 + 16) * 32;

    // stage chunk g (global k-chunk across NP products) into buffer b
    auto stage = [&](int g, int b) {
        const u16* A; const u16* B;
        if (NP == 1) { A = Ap[0]; B = Bp[0]; }
        else {
            const int p = g >> 5;
            A = (p == 0) ? Ap[0] : (p == 1) ? Ap[1] : Ap[NP - 1];
            B = (p == 0) ? Bp[0] : (p == 1) ? Bp[1] : Bp[NP - 1];
        }
        const size_t ko = (size_t)(g & 31) * 32;
        __builtin_amdgcn_global_load_lds((const AS1 u32*)(A + gA0 + ko), (AS3 u32*)&As[b][lds0], 16, 0, 0);
        __builtin_amdgcn_global_load_lds((const AS1 u32*)(A + gA1 + ko), (AS3 u32*)&As[b][lds1], 16, 0, 0);
        __builtin_amdgcn_global_load_lds((const AS1 u32*)(B + gB0 + ko), (AS3 u32*)&Bs[b][lds0], 16, 0, 0);
        __builtin_amdgcn_global_load_lds((const AS1 u32*)(B + gB1 + ko), (AS3 u32*)&Bs[b][lds1], 16, 0, 0);
    };

    // read-side swizzled LDS byte offsets (buffer 0); per-iter add of buf*8KB
    const int ccol = (quad ^ ((r16 >> 1) & 3)) * 8;
    u32 aA[4], aB[4];
#pragma unroll
    for (int m = 0; m < 4; ++m)
        aA[m] = (u32)(uintptr_t)&As[0][(wy * 64 + m * 16 + r16) * 32 + ccol];
#pragma unroll
    for (int n = 0; n < 4; ++n)
        aB[n] = (u32)(uintptr_t)&Bs[0][(wx * 64 + n * 16 + r16) * 32 + ccol];

    auto body = [&](u32 bo) {
        f16x8 af[4], bfr[4];
#pragma unroll
        for (int m = 0; m < 4; ++m) DS_READ_B128(af[m], aA[m] + bo);
#pragma unroll
        for (int n = 0; n < 4; ++n) DS_READ_B128(bfr[n], aB[n] + bo);
        asm volatile("s_waitcnt lgkmcnt(0)");
        __builtin_amdgcn_sched_barrier(0);
#pragma unroll
        for (int m = 0; m < 4; ++m)
#pragma unroll
            for (int n = 0; n < 4; ++n)
                acc[m][n] = __builtin_amdgcn_mfma_f32_16x16x32_f16(af[m], bfr[n], acc[m][n], 0, 0, 0);
        __builtin_amdgcn_sched_barrier(0);
    };

    const int NK = NP * 32;
    stage(0, 0);
    stage(1, 1);

    int buf = 0;
#pragma unroll 1
    for (int g = 0; g < NK - 1; ++g) {
        // stage g complete; stage g+1 (4 loads) stays in flight across barrier
        asm volatile("s_waitcnt vmcnt(4)");
        __builtin_amdgcn_s_barrier();
        if (g + 2 < NK) stage(g + 2, (buf == 0) ? 2 : buf - 1);
        body((u32)buf * 8192u);
        buf = (buf == 2) ? 0 : buf + 1;
    }
    asm volatile("s_waitcnt vmcnt(0)");
    __builtin_amdgcn_s_barrier();
    body((u32)buf * 8192u);
}

// ---------------- Gt = Wk @ Wq^T (fp32 out, Gt[c][d] = (Wq Wk^T)[d][c]) --------
// fp16 2-split: 3 products {lh, hl, hh} carry ~22 bits (ll dropped, rel 2^-22).
__global__ __launch_bounds__(256) void g_gemm(const u16* __restrict__ Wkh, const u16* __restrict__ Wkl,
                                              const u16* __restrict__ Wqh, const u16* __restrict__ Wql,
                                              float* __restrict__ Gt) {
    __shared__ short As[2][4096], Bs[2][4096];
    const int tid = threadIdx.x, w = tid >> 6, lane = tid & 63;
    const int wy = w >> 1, wx = w & 1, quad = lane >> 4, r16 = lane & 15;
    const int row0 = blockIdx.y * 128, col0 = blockIdx.x * 128;
    const u16* const Ap[3] = { Wkl, Wkh, Wkh };   // lh, hl, hh (small -> large)
    const u16* const Bp[3] = { Wqh, Wql, Wqh };
    f32x4 acc[4][4] = {};
    gemm_lds<3>(Ap, Bp, row0, col0, acc, As, Bs);
#pragma unroll
    for (int m = 0; m < 4; ++m)
#pragma unroll
        for (int n = 0; n < 4; ++n)
#pragma unroll
            for (int reg = 0; reg < 4; ++reg) {
                const int row = row0 + wy * 64 + m * 16 + quad * 4 + reg;
                const int col = col0 + wx * 64 + n * 16 + r16;
                Gt[row * DIM + col] = acc[m][n][reg];
            }
}

// ---------------- id<512: Y = X@G (fp32+fp16) ; id>=512: Vh = Xh@Wvt_h ---------
// id = z*512 + colt*64 + rowt -> id%8 == rowt%8: XCD round-robin pins each
// XCD's 8 A-row-tiles in its L2 (proven: FETCH 918 -> 87 MB class of fix).
__global__ __launch_bounds__(256, 3) void yv_gemm(const u16* __restrict__ Xh, const u16* __restrict__ Xl,
                                                  const u16* __restrict__ Gth, const u16* __restrict__ Gtl,
                                                  const u16* __restrict__ Wvth,
                                                  float* __restrict__ Y, u16* __restrict__ Yh, u16* __restrict__ Vh) {
    __shared__ short As[3][4096], Bs[3][4096];
    const int tid = threadIdx.x, w = tid >> 6, lane = tid & 63;
    const int wy = w >> 1, wx = w & 1, quad = lane >> 4, r16 = lane & 15;
    const int id = blockIdx.x;
    const int z = id >> 9;
    const int within = id & 511;
    const int colt = within >> 6;          // 0..7
    const int rowt = within & 63;          // 0..63
    const int row0 = rowt * 128, col0 = colt * 128;
    f32x4 acc[4][4] = {};
    if (z == 0) {
        const u16* const Ap[3] = { Xl,  Xh,  Xh  };   // lh, hl, hh
        const u16* const Bp[3] = { Gth, Gtl, Gth };
        gemm_pipe<3>(Ap, Bp, row0, col0, acc, As, Bs);
#pragma unroll
        for (int m = 0; m < 4; ++m)
#pragma unroll
            for (int n = 0; n < 4; ++n)
#pragma unroll
                for (int reg = 0; reg < 4; ++reg) {
                    const int row = row0 + wy * 64 + m * 16 + quad * 4 + reg;
                    const int col = col0 + wx * 64 + n * 16 + r16;
                    float v = acc[m][n][reg];
                    Y[row * DIM + col] = v;
                    _Float16 hb = (_Float16)v;
                    Yh[row * DIM + col] = *(u16*)&hb;
                }
    } else {
        const u16* const Ap[1] = { Xh };
        const u16* const Bp[1] = { Wvth };
        gemm_pipe<1>(Ap, Bp, row0, col0, acc, As, Bs);
#pragma unroll
        for (int m = 0; m < 4; ++m)
#pragma unroll
            for (int n = 0; n < 4; ++n)
#pragma unroll
                for (int reg = 0; reg < 4; ++reg) {
                    const int row = row0 + wy * 64 + m * 16 + quad * 4 + reg;
                    const int col = col0 + wx * 64 + n * 16 + r16;
                    _Float16 hb = (_Float16)acc[m][n][reg];
                    Vh[row * DIM + col] = *(u16*)&hb;
                }
    }
}

// ---------------- filter: S = Yh @ Xh^T (fp16), per-64col-group margin emit ----
// fp16 score error sigma ~ 10 -> MARGIN 120 (>9 sigma slack over the e^-30
// relevance window). Group max is always emitted, so the global argmax and any
// same/other-group runner-up always survive.
__global__ __launch_bounds__(256, 3) void filter_kernel(const u16* __restrict__ Yhp,
                                                        const u16* __restrict__ Xhp,
                                                        int* __restrict__ cnt,
                                                        int2* __restrict__ cand) {
    __shared__ short As[3][4096], Bs[3][4096];
    const int tid = threadIdx.x, w = tid >> 6, lane = tid & 63;
    const int wy = w >> 1, wx = w & 1, quad = lane >> 4, r16 = lane & 15;
    const int id = blockIdx.x;
    const int colt = id >> 6;              // 0..63 ; id%8 == rowt%8 (XCD pin)
    const int rowt = id & 63;              // 0..63
    const int row0 = rowt * 128, col0 = colt * 128;

    const u16* const Ap[1] = { Yhp };
    const u16* const Bp[1] = { Xhp };
    f32x4 acc[4][4] = {};
    gemm_pipe<1>(Ap, Bp, row0, col0, acc, As, Bs);

    // per row: 64-col group max -> margin filter -> emit (mechanics proven)
#pragma unroll
    for (int m = 0; m < 4; ++m) {
#pragma unroll
        for (int reg = 0; reg < 4; ++reg) {
            float mx = fmaxf(fmaxf(acc[m][0][reg], acc[m][1][reg]),
                             fmaxf(acc[m][2][reg], acc[m][3][reg]));
            mx = fmaxf(mx, __shfl_xor(mx, 1, 64));
            mx = fmaxf(mx, __shfl_xor(mx, 2, 64));
            mx = fmaxf(mx, __shfl_xor(mx, 4, 64));
            mx = fmaxf(mx, __shfl_xor(mx, 8, 64));
            const float th = mx - MARGIN;
            const int row = row0 + wy * 64 + m * 16 + quad * 4 + reg;
#pragma unroll
            for (int n = 0; n < 4; ++n) {
                float s = acc[m][n][reg];
                if (s >= th) {
                    int pos = atomicAdd(&cnt[row], 1);
                    if (pos < CAP)
                        cand[(size_t)row * CAP + pos] =
                            make_int2(col0 + wx * 64 + n * 16 + r16, __float_as_int(s));
                }
            }
        }
    }
}

// ---------------- finalize: refilter, fp64 rescore via Y·X, softmax, gather Vh -
__global__ __launch_bounds__(256) void finalize_kernel(const float* __restrict__ Y,
                                                       const float* __restrict__ X,
                                                       const u16* __restrict__ Vh,
                                                       const int* __restrict__ cnt,
                                                       const int2* __restrict__ cand,
                                                       float* __restrict__ out) {
    const int i = blockIdx.x;
    const int tid = threadIdx.x;
    const int w = tid >> 6, lane = tid & 63;
    __shared__ float  red[256];
    __shared__ int    surv[64];
    __shared__ double sprec[64];
    __shared__ float  wgt[64];
    __shared__ int    nsurv;

    const int c = min(cnt[i], CAP);
    float m = -3.0e38f;
    for (int t = tid; t < c; t += 256)
        m = fmaxf(m, __int_as_float(cand[(size_t)i * CAP + t].y));
    red[tid] = m;
    __syncthreads();
    for (int s = 128; s > 0; s >>= 1) {
        if (tid < s) red[tid] = fmaxf(red[tid], red[tid + s]);
        __syncthreads();
    }
    const float th = red[0] - MARGIN;
    if (tid == 0) nsurv = 0;
    __syncthreads();
    for (int t = tid; t < c; t += 256) {
        int2 e = cand[(size_t)i * CAP + t];
        if (__int_as_float(e.y) >= th) {
            int p = atomicAdd(&nsurv, 1);
            if (p < 64) surv[p] = e.x;
        }
    }
    __syncthreads();
    const int ns = min(nsurv, 64);
    // fp64 rescore: s_ij = y_i . x_j (exact given fp32 Y), one survivor per wave
    for (int u = w; u < ns; u += 4) {
        const int j = surv[u];
        double a = 0.0;
#pragma unroll 1
        for (int d4 = lane; d4 < DIM / 4; d4 += 64) {
            float4 yv = *(const float4*)&Y[(size_t)i * DIM + d4 * 4];
            float4 xv = *(const float4*)&X[(size_t)j * DIM + d4 * 4];
            a += (double)yv.x * (double)xv.x + (double)yv.y * (double)xv.y
               + (double)yv.z * (double)xv.z + (double)yv.w * (double)xv.w;
        }
#pragma unroll
        for (int o = 32; o > 0; o >>= 1)
            a += __shfl_down(a, o, 64);
        if (lane == 0) sprec[u] = a;
    }
    __syncthreads();
    if (tid == 0) {
        double mm = -1.0e300;
        for (int u = 0; u < ns; ++u) mm = fmax(mm, sprec[u]);
        double l = 0.0;
        for (int u = 0; u < ns; ++u) l += exp(sprec[u] - mm);
        for (int u = 0; u < ns; ++u) wgt[u] = (float)(exp(sprec[u] - mm) / l);
    }
    __syncthreads();
    // gather: 2 fp16 per thread per pass (coalesced 4B/lane)
    for (int d2 = tid; d2 < DIM / 2; d2 += 256) {
        float o0 = 0.f, o1 = 0.f;
        for (int u = 0; u < ns; ++u) {
            const u16* vp = &Vh[(size_t)surv[u] * DIM + d2 * 2];
            u32 pair = *(const u32*)vp;
            _Float16 h0 = *(_Float16*)&pair;
            u16 hi = (u16)(pair >> 16);
            _Float16 h1 = *(_Float16*)&hi;
            o0 += wgt[u] * (float)h0;
            o1 += wgt[u] * (float)h1;
        }
        out[(size_t)i * DIM + d2 * 2]     = o0;
        out[(size_t)i * DIM + d2 * 2 + 1] = o1;
    }
}

extern "C" void kernel_launch(void* const* d_in, const int* in_sizes, int n_in,
                              void* d_out, int out_size, void* d_ws, size_t ws_size,
                              hipStream_t stream) {
    const float* X  = (const float*)d_in[0];
    const float* wq = (const float*)d_in[1];
    const float* wk = (const float*)d_in[2];
    const float* wv = (const float*)d_in[3];
    float* out = (float*)d_out;

    char* ws = (char*)d_ws;
    const size_t MB = 1024 * 1024;
    u16*   Xh   = (u16*)(ws +   0 * MB);   // 16 MB
    u16*   Xl   = (u16*)(ws +  16 * MB);   // 16 MB
    u16*   Wqh  = (u16*)(ws +  32 * MB);   // 2 MB each
    u16*   Wql  = (u16*)(ws +  34 * MB);
    u16*   Wkh  = (u16*)(ws +  36 * MB);
    u16*   Wkl  = (u16*)(ws +  38 * MB);
    u16*   Wvth = (u16*)(ws +  40 * MB);
    float* Gt   = (float*)(ws + 42 * MB);  // 4 MB fp32 [c][d]
    u16*   Gth  = (u16*)(ws +  46 * MB);
    u16*   Gtl  = (u16*)(ws +  48 * MB);
    float* Y    = (float*)(ws + 64 * MB);  // 32 MB
    u16*   Yh   = (u16*)(ws +  96 * MB);   // 16 MB
    u16*   Vh   = (u16*)(ws + 112 * MB);   // 16 MB
    int*   cnt  = (int*)(ws + 128 * MB);   // 32 KB
    int2*  cand = (int2*)(ws + 129 * MB);  // 8192*256*8 = 16.8 MB

    hipMemsetAsync(cnt, 0, (size_t)NROWS * 4, stream);

    split2h<<<NROWS * DIM / 1024, 256, 0, stream>>>(X, Xh, Xl);
    split2h<<<DIM * DIM / 1024, 256, 0, stream>>>(wq, Wqh, Wql);
    split2h<<<DIM * DIM / 1024, 256, 0, stream>>>(wk, Wkh, Wkl);
    split_wvt<<<dim3(16, 16), 256, 0, stream>>>(wv, Wvth);

    g_gemm<<<dim3(8, 8), 256, 0, stream>>>(Wkh, Wkl, Wqh, Wql, Gt);
    split2h<<<DIM * DIM / 1024, 256, 0, stream>>>(Gt, Gth, Gtl);

    yv_gemm<<<1024, 256, 0, stream>>>(Xh, Xl, Gth, Gtl, Wvth, Y, Yh, Vh);

    filter_kernel<<<4096, 256, 0, stream>>>(Yh, Xh, cnt, cand);

    finalize_kernel<<<NROWS, 256, 0, stream>>>(Y, X, Vh, cnt, cand, out);
}

// Round 7
// 520.806 us; speedup vs baseline: 1.1851x; 1.0128x over previous
//
#include <hip/hip_runtime.h>
#include <hip/hip_bf16.h>
#include <math.h>

#define NROWS 8192
#define DIM   1024
#define CAP   256
#define MARGIN 120.0f

using f16x8 = __attribute__((ext_vector_type(8))) _Float16;
using f32x4 = __attribute__((ext_vector_type(4))) float;
typedef unsigned short u16;
typedef unsigned int   u32;

#define AS1 __attribute__((address_space(1)))
#define AS3 __attribute__((address_space(3)))

// inline-asm LDS read: invisible to the compiler's LDS-alias waitcnt tracking,
// so the raw-s_barrier loop keeps its COUNTED vmcnt (no auto vmcnt(0) drain).
// Ordering vs MFMA enforced by counted lgkmcnt + sched_barrier(0) (rule #18).
#define DS_READ_B128(dst, off) \
    asm volatile("ds_read_b128 %0, %1" : "=v"(dst) : "v"(off))

// ---------------- split fp32 array (len % 1024 == 0) into hi/lo fp16 planes ----
// fp16 2-split carries ~22 mantissa bits: hi + lo with lo = fp16(x - (float)hi).
__global__ __launch_bounds__(256) void split2h(const float* __restrict__ X,
                                               u16* __restrict__ H,
                                               u16* __restrict__ L) {
    const int idx = (blockIdx.x * 256 + threadIdx.x) * 4;
    float4 x = *(const float4*)&X[idx];
    float c[4] = {x.x, x.y, x.z, x.w};
    u16 h[4], l[4];
#pragma unroll
    for (int i = 0; i < 4; ++i) {
        _Float16 hh = (_Float16)c[i];
        float r = c[i] - (float)hh;
        _Float16 ll = (_Float16)r;
        h[i] = *(u16*)&hh; l[i] = *(u16*)&ll;
    }
    *(ushort4*)&H[idx] = make_ushort4(h[0], h[1], h[2], h[3]);
    *(ushort4*)&L[idx] = make_ushort4(l[0], l[1], l[2], l[3]);
}

// ---------------- transpose Wv, keep hi fp16 plane: Wvth[c][d] = f16(Wv[d][c]) -
__global__ __launch_bounds__(256) void split_wvt(const float* __restrict__ W,
                                                 u16* __restrict__ H) {
    __shared__ float t[64][65];
    const int k0 = blockIdx.x * 64, n0 = blockIdx.y * 64;
    const int c = threadIdx.x & 63, r4 = threadIdx.x >> 6;
#pragma unroll
    for (int i = 0; i < 16; ++i) {
        int k = r4 + i * 4;
        t[k][c] = W[(size_t)(k0 + k) * DIM + n0 + c];
    }
    __syncthreads();
#pragma unroll
    for (int i = 0; i < 16; ++i) {
        int n = r4 + i * 4;
        _Float16 hb = (_Float16)t[c][n];
        H[(n0 + n) * DIM + k0 + c] = *(u16*)&hb;
    }
}

// ---------------- R4-proven 2-buf engine (g_gemm only; small, off hot path) ---
template<int NP>
__device__ __forceinline__ void gemm_lds(const u16* const (&Ap)[NP],
                                         const u16* const (&Bp)[NP],
                                         int row0, int col0, f32x4 (&acc)[4][4],
                                         short (&As)[2][4096], short (&Bs)[2][4096]) {
    const int tid = threadIdx.x;
    const int w = tid >> 6, lane = tid & 63;
    const int wy = w >> 1, wx = w & 1;
    const int quad = lane >> 4, r16 = lane & 15;

    const int    srow   = w * 32 + (lane >> 2);
    const int    schunk = ((lane & 3) ^ ((lane >> 3) & 3)) * 8;
    const size_t gA0 = (size_t)(row0 + srow) * DIM + schunk;
    const size_t gA1 = gA0 + (size_t)16 * DIM;
    const size_t gB0 = (size_t)(col0 + srow) * DIM + schunk;
    const size_t gB1 = gB0 + (size_t)16 * DIM;
    const int lds0 = (w * 32) * 32;
    const int lds1 = (w * 32 + 16) * 32;

    auto issue = [&](const u16* A, const u16* B, size_t ko, int buf) {
        __builtin_amdgcn_global_load_lds((const AS1 u32*)(A + gA0 + ko), (AS3 u32*)&As[buf][lds0], 16, 0, 0);
        __builtin_amdgcn_global_load_lds((const AS1 u32*)(A + gA1 + ko), (AS3 u32*)&As[buf][lds1], 16, 0, 0);
        __builtin_amdgcn_global_load_lds((const AS1 u32*)(B + gB0 + ko), (AS3 u32*)&Bs[buf][lds0], 16, 0, 0);
        __builtin_amdgcn_global_load_lds((const AS1 u32*)(B + gB1 + ko), (AS3 u32*)&Bs[buf][lds1], 16, 0, 0);
    };

    issue(Ap[0], Bp[0], 0, 0);

    const int ccol = (quad ^ ((r16 >> 1) & 3)) * 8;

    int pp = 0;
#pragma unroll
    for (int p = 0; p < NP; ++p) {
        const u16* A = Ap[p];
        const u16* B = Bp[p];
        const u16* An = (p + 1 < NP) ? Ap[p + 1] : A;
        const u16* Bn = (p + 1 < NP) ? Bp[p + 1] : B;
        const bool more = (p + 1 < NP);
        for (int i = 0; i < 32; ++i) {
            __syncthreads();
            const int cur = pp, nxt = pp ^ 1;
            if (i < 31)      issue(A, B, (size_t)(i + 1) * 32, nxt);
            else if (more)   issue(An, Bn, 0, nxt);
            const short* AsC = As[cur];
            const short* BsC = Bs[cur];
            f16x8 af[4], bfr[4];
#pragma unroll
            for (int m = 0; m < 4; ++m)
                af[m] = *(const f16x8*)&AsC[(wy * 64 + m * 16 + r16) * 32 + ccol];
#pragma unroll
            for (int n = 0; n < 4; ++n)
                bfr[n] = *(const f16x8*)&BsC[(wx * 64 + n * 16 + r16) * 32 + ccol];
#pragma unroll
            for (int m = 0; m < 4; ++m)
#pragma unroll
                for (int n = 0; n < 4; ++n)
                    acc[m][n] = __builtin_amdgcn_mfma_f32_16x16x32_f16(af[m], bfr[n], acc[m][n], 0, 0, 0);
            pp ^= 1;
        }
    }
}

// ---------------- 128x128 NT fp16 engine, 3-buf + staggered lgkmcnt -----------
// R7 = R6 skeleton (3-buf, counted vmcnt(4), raw s_barrier; prefetch distance
// 2) with the body's read->MFMA fence made FINE-GRAINED. R6's lgkmcnt(0) made
// every wave wait for all 8 ds_reads before any MFMA; after each barrier all
// 12 resident waves burst 96 correlated ds_read_b128 into the shared per-CU
// LDS pipe (~12 cyc each -> ~1150 cyc queue) with the MFMA pipe idle, then
// computed -- measured 1229 cyc/block-iter vs ~400 pipe demand. R7 issues
// {bf0-3, af0-3} and interleaves counted waits (LDS ops complete in order per
// wave, so lgkmcnt(N) == first 8-N reads landed):
//   lgkmcnt(3) -> MFMA m=0 (needs bf0-3,af0) -> lgkmcnt(2) -> m=1 -> ... ->
//   lgkmcnt(0) -> m=3.
// Each wave starts computing after 5 reads; the remaining queue drain overlaps
// its own (and other waves') MFMAs -- the m97-compiler schedule (lgkmcnt
// 4/3/1/0) reproduced inside the counted-vmcnt loop. sched_barrier(0) after
// each waitcnt pins MFMAs below it (rule #18). No new live state: VGPR stays
// ~68 (R5 lesson: the 64+64 budget is a knife edge).
template<int NP>
__device__ __forceinline__ void gemm_pipe(const u16* const (&Ap)[NP],
                                          const u16* const (&Bp)[NP],
                                          int row0, int col0, f32x4 (&acc)[4][4],
                                          short (&As)[3][4096], short (&Bs)[3][4096]) {
    const int tid = threadIdx.x;
    const int w = tid >> 6, lane = tid & 63;
    const int wy = w >> 1, wx = w & 1;
    const int quad = lane >> 4, r16 = lane & 15;

    const int    srow   = w * 32 + (lane >> 2);
    const int    schunk = ((lane & 3) ^ ((lane >> 3) & 3)) * 8;
    const size_t gA0 = (size_t)(row0 + srow) * DIM + schunk;
    const size_t gA1 = gA0 + (size_t)16 * DIM;
    const size_t gB0 = (size_t)(col0 + srow) * DIM + schunk;
    const size_t gB1 = gB0 + (size_t)16 * DIM;
    const int lds0 = (w * 32) * 32;
    const int lds1 = (w * 32 + 16) * 32;

    // stage chunk g (global k-chunk across NP products) into buffer b
    auto stage = [&](int g, int b) {
        const u16* A; const u16* B;
        if (NP == 1) { A = Ap[0]; B = Bp[0]; }
        else {
            const int p = g >> 5;
            A = (p == 0) ? Ap[0] : (p == 1) ? Ap[1] : Ap[NP - 1];
            B = (p == 0) ? Bp[0] : (p == 1) ? Bp[1] : Bp[NP - 1];
        }
        const size_t ko = (size_t)(g & 31) * 32;
        __builtin_amdgcn_global_load_lds((const AS1 u32*)(A + gA0 + ko), (AS3 u32*)&As[b][lds0], 16, 0, 0);
        __builtin_amdgcn_global_load_lds((const AS1 u32*)(A + gA1 + ko), (AS3 u32*)&As[b][lds1], 16, 0, 0);
        __builtin_amdgcn_global_load_lds((const AS1 u32*)(B + gB0 + ko), (AS3 u32*)&Bs[b][lds0], 16, 0, 0);
        __builtin_amdgcn_global_load_lds((const AS1 u32*)(B + gB1 + ko), (AS3 u32*)&Bs[b][lds1], 16, 0, 0);
    };

    // read-side swizzled LDS byte offsets (buffer 0); per-iter add of buf*8KB
    const int ccol = (quad ^ ((r16 >> 1) & 3)) * 8;
    u32 aA[4], aB[4];
#pragma unroll
    for (int m = 0; m < 4; ++m)
        aA[m] = (u32)(uintptr_t)&As[0][(wy * 64 + m * 16 + r16) * 32 + ccol];
#pragma unroll
    for (int n = 0; n < 4; ++n)
        aB[n] = (u32)(uintptr_t)&Bs[0][(wx * 64 + n * 16 + r16) * 32 + ccol];

    auto body = [&](u32 bo) {
        f16x8 af[4], bfr[4];
        // issue order matters: bf first, then af -> lgkmcnt(3) == {bf0-3, af0}
#pragma unroll
        for (int n = 0; n < 4; ++n) DS_READ_B128(bfr[n], aB[n] + bo);
#pragma unroll
        for (int m = 0; m < 4; ++m) DS_READ_B128(af[m], aA[m] + bo);

        asm volatile("s_waitcnt lgkmcnt(3)");
        __builtin_amdgcn_sched_barrier(0);
#pragma unroll
        for (int n = 0; n < 4; ++n)
            acc[0][n] = __builtin_amdgcn_mfma_f32_16x16x32_f16(af[0], bfr[n], acc[0][n], 0, 0, 0);

        asm volatile("s_waitcnt lgkmcnt(2)");
        __builtin_amdgcn_sched_barrier(0);
#pragma unroll
        for (int n = 0; n < 4; ++n)
            acc[1][n] = __builtin_amdgcn_mfma_f32_16x16x32_f16(af[1], bfr[n], acc[1][n], 0, 0, 0);

        asm volatile("s_waitcnt lgkmcnt(1)");
        __builtin_amdgcn_sched_barrier(0);
#pragma unroll
        for (int n = 0; n < 4; ++n)
            acc[2][n] = __builtin_amdgcn_mfma_f32_16x16x32_f16(af[2], bfr[n], acc[2][n], 0, 0, 0);

        asm volatile("s_waitcnt lgkmcnt(0)");
        __builtin_amdgcn_sched_barrier(0);
#pragma unroll
        for (int n = 0; n < 4; ++n)
            acc[3][n] = __builtin_amdgcn_mfma_f32_16x16x32_f16(af[3], bfr[n], acc[3][n], 0, 0, 0);
        __builtin_amdgcn_sched_barrier(0);
    };

    const int NK = NP * 32;
    stage(0, 0);
    stage(1, 1);

    int buf = 0;
#pragma unroll 1
    for (int g = 0; g < NK - 1; ++g) {
        // stage g complete; stage g+1 (4 loads) stays in flight across barrier
        asm volatile("s_waitcnt vmcnt(4)");
        __builtin_amdgcn_s_barrier();
        if (g + 2 < NK) stage(g + 2, (buf == 0) ? 2 : buf - 1);
        body((u32)buf * 8192u);
        buf = (buf == 2) ? 0 : buf + 1;
    }
    asm volatile("s_waitcnt vmcnt(0)");
    __builtin_amdgcn_s_barrier();
    body((u32)buf * 8192u);
}

// ---------------- Gt = Wk @ Wq^T (fp32 out, Gt[c][d] = (Wq Wk^T)[d][c]) --------
// fp16 2-split: 3 products {lh, hl, hh} carry ~22 bits (ll dropped, rel 2^-22).
__global__ __launch_bounds__(256) void g_gemm(const u16* __restrict__ Wkh, const u16* __restrict__ Wkl,
                                              const u16* __restrict__ Wqh, const u16* __restrict__ Wql,
                                              float* __restrict__ Gt) {
    __shared__ short As[2][4096], Bs[2][4096];
    const int tid = threadIdx.x, w = tid >> 6, lane = tid & 63;
    const int wy = w >> 1, wx = w & 1, quad = lane >> 4, r16 = lane & 15;
    const int row0 = blockIdx.y * 128, col0 = blockIdx.x * 128;
    const u16* const Ap[3] = { Wkl, Wkh, Wkh };   // lh, hl, hh (small -> large)
    const u16* const Bp[3] = { Wqh, Wql, Wqh };
    f32x4 acc[4][4] = {};
    gemm_lds<3>(Ap, Bp, row0, col0, acc, As, Bs);
#pragma unroll
    for (int m = 0; m < 4; ++m)
#pragma unroll
        for (int n = 0; n < 4; ++n)
#pragma unroll
            for (int reg = 0; reg < 4; ++reg) {
                const int row = row0 + wy * 64 + m * 16 + quad * 4 + reg;
                const int col = col0 + wx * 64 + n * 16 + r16;
                Gt[row * DIM + col] = acc[m][n][reg];
            }
}

// ---------------- id<512: Y = X@G (fp32+fp16) ; id>=512: Vh = Xh@Wvt_h ---------
// id = z*512 + colt*64 + rowt -> id%8 == rowt%8: XCD round-robin pins each
// XCD's 8 A-row-tiles in its L2 (proven: FETCH 918 -> 87 MB class of fix).
__global__ __launch_bounds__(256, 3) void yv_gemm(const u16* __restrict__ Xh, const u16* __restrict__ Xl,
                                                  const u16* __restrict__ Gth, const u16* __restrict__ Gtl,
                                                  const u16* __restrict__ Wvth,
                                                  float* __restrict__ Y, u16* __restrict__ Yh, u16* __restrict__ Vh) {
    __shared__ short As[3][4096], Bs[3][4096];
    const int tid = threadIdx.x, w = tid >> 6, lane = tid & 63;
    const int wy = w >> 1, wx = w & 1, quad = lane >> 4, r16 = lane & 15;
    const int id = blockIdx.x;
    const int z = id >> 9;
    const int within = id & 511;
    const int colt = within >> 6;          // 0..7
    const int rowt = within & 63;          // 0..63
    const int row0 = rowt * 128, col0 = colt * 128;
    f32x4 acc[4][4] = {};
    if (z == 0) {
        const u16* const Ap[3] = { Xl,  Xh,  Xh  };   // lh, hl, hh
        const u16* const Bp[3] = { Gth, Gtl, Gth };
        gemm_pipe<3>(Ap, Bp, row0, col0, acc, As, Bs);
#pragma unroll
        for (int m = 0; m < 4; ++m)
#pragma unroll
            for (int n = 0; n < 4; ++n)
#pragma unroll
                for (int reg = 0; reg < 4; ++reg) {
                    const int row = row0 + wy * 64 + m * 16 + quad * 4 + reg;
                    const int col = col0 + wx * 64 + n * 16 + r16;
                    float v = acc[m][n][reg];
                    Y[row * DIM + col] = v;
                    _Float16 hb = (_Float16)v;
                    Yh[row * DIM + col] = *(u16*)&hb;
                }
    } else {
        const u16* const Ap[1] = { Xh };
        const u16* const Bp[1] = { Wvth };
        gemm_pipe<1>(Ap, Bp, row0, col0, acc, As, Bs);
#pragma unroll
        for (int m = 0; m < 4; ++m)
#pragma unroll
            for (int n = 0; n < 4; ++n)
#pragma unroll
                for (int reg = 0; reg < 4; ++reg) {
                    const int row = row0 + wy * 64 + m * 16 + quad * 4 + reg;
                    const int col = col0 + wx * 64 + n * 16 + r16;
                    _Float16 hb = (_Float16)acc[m][n][reg];
                    Vh[row * DIM + col] = *(u16*)&hb;
                }
    }
}

// ---------------- filter: S = Yh @ Xh^T (fp16), per-64col-group margin emit ----
// fp16 score error sigma ~ 10 -> MARGIN 120 (>9 sigma slack over the e^-30
// relevance window). Group max is always emitted, so the global argmax and any
// same/other-group runner-up always survive.
__global__ __launch_bounds__(256, 3) void filter_kernel(const u16* __restrict__ Yhp,
                                                        const u16* __restrict__ Xhp,
                                                        int* __restrict__ cnt,
                                                        int2* __restrict__ cand) {
    __shared__ short As[3][4096], Bs[3][4096];
    const int tid = threadIdx.x, w = tid >> 6, lane = tid & 63;
    const int wy = w >> 1, wx = w & 1, quad = lane >> 4, r16 = lane & 15;
    const int id = blockIdx.x;
    const int colt = id >> 6;              // 0..63 ; id%8 == rowt%8 (XCD pin)
    const int rowt = id & 63;              // 0..63
    const int row0 = rowt * 128, col0 = colt * 128;

    const u16* const Ap[1] = { Yhp };
    const u16* const Bp[1] = { Xhp };
    f32x4 acc[4][4] = {};
    gemm_pipe<1>(Ap, Bp, row0, col0, acc, As, Bs);

    // per row: 64-col group max -> margin filter -> emit (mechanics proven)
#pragma unroll
    for (int m = 0; m < 4; ++m) {
#pragma unroll
        for (int reg = 0; reg < 4; ++reg) {
            float mx = fmaxf(fmaxf(acc[m][0][reg], acc[m][1][reg]),
                             fmaxf(acc[m][2][reg], acc[m][3][reg]));
            mx = fmaxf(mx, __shfl_xor(mx, 1, 64));
            mx = fmaxf(mx, __shfl_xor(mx, 2, 64));
            mx = fmaxf(mx, __shfl_xor(mx, 4, 64));
            mx = fmaxf(mx, __shfl_xor(mx, 8, 64));
            const float th = mx - MARGIN;
            const int row = row0 + wy * 64 + m * 16 + quad * 4 + reg;
#pragma unroll
            for (int n = 0; n < 4; ++n) {
                float s = acc[m][n][reg];
                if (s >= th) {
                    int pos = atomicAdd(&cnt[row], 1);
                    if (pos < CAP)
                        cand[(size_t)row * CAP + pos] =
                            make_int2(col0 + wx * 64 + n * 16 + r16, __float_as_int(s));
                }
            }
        }
    }
}

// ---------------- finalize: refilter, fp64 rescore via Y·X, softmax, gather Vh -
__global__ __launch_bounds__(256) void finalize_kernel(const float* __restrict__ Y,
                                                       const float* __restrict__ X,
                                                       const u16* __restrict__ Vh,
                                                       const int* __restrict__ cnt,
                                                       const int2* __restrict__ cand,
                                                       float* __restrict__ out) {
    const int i = blockIdx.x;
    const int tid = threadIdx.x;
    const int w = tid >> 6, lane = tid & 63;
    __shared__ float  red[256];
    __shared__ int    surv[64];
    __shared__ double sprec[64];
    __shared__ float  wgt[64];
    __shared__ int    nsurv;

    const int c = min(cnt[i], CAP);
    float m = -3.0e38f;
    for (int t = tid; t < c; t += 256)
        m = fmaxf(m, __int_as_float(cand[(size_t)i * CAP + t].y));
    red[tid] = m;
    __syncthreads();
    for (int s = 128; s > 0; s >>= 1) {
        if (tid < s) red[tid] = fmaxf(red[tid], red[tid + s]);
        __syncthreads();
    }
    const float th = red[0] - MARGIN;
    if (tid == 0) nsurv = 0;
    __syncthreads();
    for (int t = tid; t < c; t += 256) {
        int2 e = cand[(size_t)i * CAP + t];
        if (__int_as_float(e.y) >= th) {
            int p = atomicAdd(&nsurv, 1);
            if (p < 64) surv[p] = e.x;
        }
    }
    __syncthreads();
    const int ns = min(nsurv, 64);
    // fp64 rescore: s_ij = y_i . x_j (exact given fp32 Y), one survivor per wave
    for (int u = w; u < ns; u += 4) {
        const int j = surv[u];
        double a = 0.0;
#pragma unroll 1
        for (int d4 = lane; d4 < DIM / 4; d4 += 64) {
            float4 yv = *(const float4*)&Y[(size_t)i * DIM + d4 * 4];
            float4 xv = *(const float4*)&X[(size_t)j * DIM + d4 * 4];
            a += (double)yv.x * (double)xv.x + (double)yv.y * (double)xv.y
               + (double)yv.z * (double)xv.z + (double)yv.w * (double)xv.w;
        }
#pragma unroll
        for (int o = 32; o > 0; o >>= 1)
            a += __shfl_down(a, o, 64);
        if (lane == 0) sprec[u] = a;
    }
    __syncthreads();
    if (tid == 0) {
        double mm = -1.0e300;
        for (int u = 0; u < ns; ++u) mm = fmax(mm, sprec[u]);
        double l = 0.0;
        for (int u = 0; u < ns; ++u) l += exp(sprec[u] - mm);
        for (int u = 0; u < ns; ++u) wgt[u] = (float)(exp(sprec[u] - mm) / l);
    }
    __syncthreads();
    // gather: 2 fp16 per thread per pass (coalesced 4B/lane)
    for (int d2 = tid; d2 < DIM / 2; d2 += 256) {
        float o0 = 0.f, o1 = 0.f;
        for (int u = 0; u < ns; ++u) {
            const u16* vp = &Vh[(size_t)surv[u] * DIM + d2 * 2];
            u32 pair = *(const u32*)vp;
            _Float16 h0 = *(_Float16*)&pair;
            u16 hi = (u16)(pair >> 16);
            _Float16 h1 = *(_Float16*)&hi;
            o0 += wgt[u] * (float)h0;
            o1 += wgt[u] * (float)h1;
        }
        out[(size_t)i * DIM + d2 * 2]     = o0;
        out[(size_t)i * DIM + d2 * 2 + 1] = o1;
    }
}

extern "C" void kernel_launch(void* const* d_in, const int* in_sizes, int n_in,
                              void* d_out, int out_size, void* d_ws, size_t ws_size,
                              hipStream_t stream) {
    const float* X  = (const float*)d_in[0];
    const float* wq = (const float*)d_in[1];
    const float* wk = (const float*)d_in[2];
    const float* wv = (const float*)d_in[3];
    float* out = (float*)d_out;

    char* ws = (char*)d_ws;
    const size_t MB = 1024 * 1024;
    u16*   Xh   = (u16*)(ws +   0 * MB);   // 16 MB
    u16*   Xl   = (u16*)(ws +  16 * MB);   // 16 MB
    u16*   Wqh  = (u16*)(ws +  32 * MB);   // 2 MB each
    u16*   Wql  = (u16*)(ws +  34 * MB);
    u16*   Wkh  = (u16*)(ws +  36 * MB);
    u16*   Wkl  = (u16*)(ws +  38 * MB);
    u16*   Wvth = (u16*)(ws +  40 * MB);
    float* Gt   = (float*)(ws + 42 * MB);  // 4 MB fp32 [c][d]
    u16*   Gth  = (u16*)(ws +  46 * MB);
    u16*   Gtl  = (u16*)(ws +  48 * MB);
    float* Y    = (float*)(ws + 64 * MB);  // 32 MB
    u16*   Yh   = (u16*)(ws +  96 * MB);   // 16 MB
    u16*   Vh   = (u16*)(ws + 112 * MB);   // 16 MB
    int*   cnt  = (int*)(ws + 128 * MB);   // 32 KB
    int2*  cand = (int2*)(ws + 129 * MB);  // 8192*256*8 = 16.8 MB

    hipMemsetAsync(cnt, 0, (size_t)NROWS * 4, stream);

    split2h<<<NROWS * DIM / 1024, 256, 0, stream>>>(X, Xh, Xl);
    split2h<<<DIM * DIM / 1024, 256, 0, stream>>>(wq, Wqh, Wql);
    split2h<<<DIM * DIM / 1024, 256, 0, stream>>>(wk, Wkh, Wkl);
    split_wvt<<<dim3(16, 16), 256, 0, stream>>>(wv, Wvth);

    g_gemm<<<dim3(8, 8), 256, 0, stream>>>(Wkh, Wkl, Wqh, Wql, Gt);
    split2h<<<DIM * DIM / 1024, 256, 0, stream>>>(Gt, Gth, Gtl);

    yv_gemm<<<1024, 256, 0, stream>>>(Xh, Xl, Gth, Gtl, Wvth, Y, Yh, Vh);

    filter_kernel<<<4096, 256, 0, stream>>>(Yh, Xh, cnt, cand);

    finalize_kernel<<<NROWS, 256, 0, stream>>>(Y, X, Vh, cnt, cand, out);
}